// Round 17
// baseline (1128.457 us; speedup 1.0000x reference)
//
#include <hip/hip_runtime.h>
#include <math.h>

typedef __attribute__((ext_vector_type(4))) float f32x4;
typedef __attribute__((ext_vector_type(8))) short s16x8;
typedef __attribute__((ext_vector_type(4))) short s16x4;

#define NN 32768      // nodes
#define NE 102400     // edges
#define HD 128        // H
#define EED 64        // edge enc dim
#define MSGD 256
#define NG 512        // graphs
#define EPG 200       // edges per graph
#define NP 256        // pairs
#define SKD 32

__device__ inline short f2bf(float x){
  union{float f; unsigned u;} z; z.f=x;
  unsigned r = (z.u + 0x7fffu + ((z.u>>16)&1u)) >> 16;
  return (short)r;
}
__device__ inline float bf2f(unsigned short u){
  union{unsigned u; float f;} z; z.u = ((unsigned)u)<<16; return z.f;
}
__device__ inline float frcp(float x){
  float r; asm("v_rcp_f32 %0, %1" : "=v"(r) : "v"(x)); return r;
}

// ---------------- node encoder: h (f32) + hb (bf16) ----------------
__global__ void __launch_bounds__(256) k_enc_node(const float* __restrict__ nf,
    const float* __restrict__ W, const float* __restrict__ b,
    float* __restrict__ h, short* __restrict__ hb){
  __shared__ float Ws[16*128];
  int t = threadIdx.x;
  for (int i=t;i<16*128;i+=256) Ws[i]=W[i];
  __syncthreads();
  int node = blockIdx.x*2 + (t>>7);
  int f = t & 127;
  const float* x = nf + node*16;
  float acc = b[f];
  #pragma unroll
  for (int k=0;k<16;k++) acc = fmaf(x[k], Ws[k*128+f], acc);
  h[node*HD+f] = acc;
  hb[node*HD+f] = f2bf(acc);
}

// ---------------- edge encoder: bf16 output ----------------
__global__ void __launch_bounds__(256) k_enc_edge(const float* __restrict__ ef,
    const float* __restrict__ W, const float* __restrict__ b, short* __restrict__ eeb){
  __shared__ float Ws[16*64];
  int t = threadIdx.x;
  for (int i=t;i<16*64;i+=256) Ws[i]=W[i];
  __syncthreads();
  int edge = blockIdx.x*4 + (t>>6);
  int f = t & 63;
  const float* x = ef + edge*16;
  float acc = b[f];
  #pragma unroll
  for (int k=0;k<16;k++) acc = fmaf(x[k], Ws[k*64+f], acc);
  eeb[edge*EED+f] = f2bf(acc);
}

// ---------------- all weight packs in one launch ----------------
// Wih gets permK: its K rows follow the permuted aggb storage order
// (within each 64-block: stored k' = lr*4+ct <-> orig k = ct*16+lr).
__global__ void __launch_bounds__(256) k_pack_all(
    const float* __restrict__ mw1, const float* __restrict__ rw1,
    const float* __restrict__ mw2, const float* __restrict__ rw2,
    const float* __restrict__ wih, const float* __restrict__ whh,
    const float* __restrict__ skw1, const float* __restrict__ skw2,
    short* __restrict__ w1f_p, short* __restrict__ w1r_p,
    short* __restrict__ w2f_p, short* __restrict__ w2r_p,
    short* __restrict__ wih_p, short* __restrict__ whh_p,
    short* __restrict__ skw1_p, short* __restrict__ skw2_p){
  int b = blockIdx.x;
  const float* W; short* dst; int K, N; int permK = 0;
  if      (b < 40) { W=mw1;  dst=w1f_p;  K=320; N=256; }
  else if (b < 80) { W=rw1;  dst=w1r_p;  K=320; N=256; b-=40; }
  else if (b < 112){ W=mw2;  dst=w2f_p;  K=256; N=256; b-=80; }
  else if (b < 144){ W=rw2;  dst=w2r_p;  K=256; N=256; b-=112; }
  else if (b < 192){ W=wih;  dst=wih_p;  K=256; N=384; b-=144; permK=1; }
  else if (b < 216){ W=whh;  dst=whh_p;  K=128; N=384; b-=192; }
  else if (b < 220){ W=skw1; dst=skw1_p; K=256; N=32;  b-=216; }
  else             { W=skw2; dst=skw2_p; K=32;  N=32;  b-=220; }
  int NT = N >> 4;
  int i = b*256 + (int)threadIdx.x;
  if (i >= (K/32)*NT*64) return;
  int l = i & 63, tile = i >> 6;
  int nt = tile % NT, kt = tile / NT;
  int lr = l & 15, lq = l >> 4;
  s16x8 v;
  #pragma unroll
  for (int j=0;j<8;j++){
    int k = kt*32 + lq*8 + j;
    if (permK){
      int blk = k & ~63, w64 = k & 63;
      k = blk + (w64 & 3)*16 + (w64 >> 2);
    }
    v[j] = f2bf(W[(size_t)k*N + nt*16 + lr]);
  }
  *((s16x8*)dst + i) = v;
}

// ---------------- CSR build ----------------
__global__ void __launch_bounds__(256) k_csr_count(const int* __restrict__ fidx,
    const int* __restrict__ tidx, int* __restrict__ cur_in, int* __restrict__ cur_out){
  int e = blockIdx.x*256 + threadIdx.x;
  if (e >= NE) return;
  atomicAdd(&cur_in[tidx[e]], 1);
  atomicAdd(&cur_out[fidx[e]], 1);
}
__global__ void k_csr_scan(int* __restrict__ cur_in, int* __restrict__ start_in,
    int* __restrict__ cur_out, int* __restrict__ start_out){
  if (threadIdx.x) return;
  int g = blockIdx.x;
  int n0 = g*64, base = g*EPG;
  int run = base;
  for (int i=0;i<64;i++){ int c=cur_in[n0+i]; start_in[n0+i]=run; cur_in[n0+i]=run; run+=c; }
  run = base;
  for (int i=0;i<64;i++){ int c=cur_out[n0+i]; start_out[n0+i]=run; cur_out[n0+i]=run; run+=c; }
}
__global__ void __launch_bounds__(256) k_csr_fill(const int* __restrict__ fidx,
    const int* __restrict__ tidx, int* __restrict__ cur_in, int* __restrict__ cur_out,
    int* __restrict__ list_in, int* __restrict__ list_out){
  int e = blockIdx.x*256 + threadIdx.x;
  if (e >= NE) return;
  int p1 = atomicAdd(&cur_in[tidx[e]], 1);  list_in[p1] = e;
  int p2 = atomicAdd(&cur_out[fidx[e]], 1); list_out[p2] = e;
}

// ---------------- message MLPs (fwd+rev): permuted direct stores ----------------
// mf/mr columns stored as c' = blk64 + lr*4 + ct (orig c = blk64 + ct*16 + lr).
// Consumers: k_gather (order-oblivious) -> aggb (same order) -> k_gru
// (Wih packed with matching K-permutation). Bit-identical numerics.
__global__ void __launch_bounds__(256,2) k_msg_both(const short* __restrict__ hb,
    const short* __restrict__ eeb, const int* __restrict__ from_idx, const int* __restrict__ to_idx,
    const short* __restrict__ w1f, const float* __restrict__ b1f,
    const short* __restrict__ w2f, const float* __restrict__ b2f,
    const short* __restrict__ w1r, const float* __restrict__ b1r,
    const short* __restrict__ w2r, const float* __restrict__ b2r,
    short* __restrict__ mf, short* __restrict__ mr){
  __shared__ __align__(16) short Xs[64][328];
  __shared__ __align__(16) short Ys[64][264];
  __shared__ int sidx[64], didx[64];
  int t = threadIdx.x;
  int e0 = blockIdx.x*64;
  if (t < 64){ sidx[t]=from_idx[e0+t]; didx[t]=to_idx[e0+t]; }
  __syncthreads();
  for (int i=t; i<64*40; i+=256){
    int r = i/40, c8 = (i - r*40)*8;
    const short* src;
    if (c8 < 128)      src = hb + (size_t)sidx[r]*HD + c8;
    else if (c8 < 256) src = hb + (size_t)didx[r]*HD + (c8-128);
    else               src = eeb + (size_t)(e0+r)*EED + (c8-256);
    *(s16x8*)&Xs[r][c8] = *(const s16x8*)src;
  }
  __syncthreads();

  int wv = t>>6, l = t&63, lr = l&15, lq = l>>4;
  int cbase = wv*64;

  for (int dir=0; dir<2; dir++){
    const s16x8* W1v = (const s16x8*)(dir ? w1r : w1f);
    const float* B1  = dir ? b1r : b1f;
    const s16x8* W2v = (const s16x8*)(dir ? w2r : w2f);
    const float* B2  = dir ? b2r : b2f;

    f32x4 acc[4][4];
    #pragma unroll
    for (int ct=0; ct<4; ct++){
      float bb = B1[cbase + ct*16 + lr];
      #pragma unroll
      for (int rt=0; rt<4; rt++) acc[rt][ct] = (f32x4){bb,bb,bb,bb};
    }
    {
      s16x8 a0[4], b0[4], b1[4];
      int sc0 = dir ? 4 : 0;
      #pragma unroll
      for (int rt=0;rt<4;rt++) a0[rt] = *(const s16x8*)&Xs[rt*16+lr][sc0*32 + lq*8];
      #pragma unroll
      for (int ct=0;ct<4;ct++) b0[ct] = W1v[(size_t)(0*16 + wv*4 + ct)*64 + l];
      #pragma unroll
      for (int ct=0;ct<4;ct++) b1[ct] = W1v[(size_t)(1*16 + wv*4 + ct)*64 + l];
      #pragma unroll
      for (int kt=0; kt<10; kt++){
        s16x8 an[4], bn[4];
        if (kt < 9){
          int sc = (dir && (kt+1)<8) ? ((kt+1)^4) : (kt+1);
          #pragma unroll
          for (int rt=0;rt<4;rt++) an[rt] = *(const s16x8*)&Xs[rt*16+lr][sc*32 + lq*8];
        }
        if (kt < 8){
          #pragma unroll
          for (int ct=0;ct<4;ct++) bn[ct] = W1v[(size_t)((kt+2)*16 + wv*4 + ct)*64 + l];
        }
        #pragma unroll
        for (int rt=0; rt<4; rt++)
          #pragma unroll
          for (int ct=0; ct<4; ct++)
            acc[rt][ct] = __builtin_amdgcn_mfma_f32_16x16x32_bf16(a0[rt], b0[ct], acc[rt][ct], 0,0,0);
        #pragma unroll
        for (int i=0;i<4;i++){ a0[i]=an[i]; b0[i]=b1[i]; b1[i]=bn[i]; }
      }
    }
    if (dir) __syncthreads();   // dir0's layer-2 Ys reads complete before overwrite
    #pragma unroll
    for (int rt=0; rt<4; rt++)
      #pragma unroll
      for (int ct=0; ct<4; ct++)
        #pragma unroll
        for (int r=0; r<4; r++)
          Ys[rt*16 + lq*4 + r][cbase + ct*16 + lr] = f2bf(fmaxf(acc[rt][ct][r], 0.f));
    __syncthreads();

    f32x4 acc2[4][4];
    #pragma unroll
    for (int ct=0; ct<4; ct++){
      float bb = B2[cbase + ct*16 + lr];
      #pragma unroll
      for (int rt=0; rt<4; rt++) acc2[rt][ct] = (f32x4){bb,bb,bb,bb};
    }
    {
      s16x8 a0[4], b0[4], b1[4];
      #pragma unroll
      for (int rt=0;rt<4;rt++) a0[rt] = *(const s16x8*)&Ys[rt*16+lr][lq*8];
      #pragma unroll
      for (int ct=0;ct<4;ct++) b0[ct] = W2v[(size_t)(0*16 + wv*4 + ct)*64 + l];
      #pragma unroll
      for (int ct=0;ct<4;ct++) b1[ct] = W2v[(size_t)(1*16 + wv*4 + ct)*64 + l];
      #pragma unroll
      for (int kt=0; kt<8; kt++){
        s16x8 an[4], bn[4];
        if (kt < 7){
          #pragma unroll
          for (int rt=0;rt<4;rt++) an[rt] = *(const s16x8*)&Ys[rt*16+lr][(kt+1)*32 + lq*8];
        }
        if (kt < 6){
          #pragma unroll
          for (int ct=0;ct<4;ct++) bn[ct] = W2v[(size_t)((kt+2)*16 + wv*4 + ct)*64 + l];
        }
        #pragma unroll
        for (int rt=0; rt<4; rt++)
          #pragma unroll
          for (int ct=0; ct<4; ct++)
            acc2[rt][ct] = __builtin_amdgcn_mfma_f32_16x16x32_bf16(a0[rt], b0[ct], acc2[rt][ct], 0,0,0);
        #pragma unroll
        for (int i=0;i<4;i++){ a0[i]=an[i]; b0[i]=b1[i]; b1[i]=bn[i]; }
      }
    }
    // direct permuted stores: 4 consecutive bf16 per row per thread (8B), 128B/quarter-wave
    {
      short* dst = (dir ? mr : mf) + (size_t)e0*MSGD;
      #pragma unroll
      for (int rt=0; rt<4; rt++)
        #pragma unroll
        for (int r=0; r<4; r++){
          int row = rt*16 + lq*4 + r;
          s16x4 o;
          #pragma unroll
          for (int ct=0; ct<4; ct++) o[ct] = f2bf(acc2[rt][ct][r]);
          *(s16x4*)&dst[(size_t)row*MSGD + cbase + lr*4] = o;
        }
    }
  }
}

// ---------------- gather: aggb[n] (bf16, permuted order) = sum_in mf + sum_out mr ----------------
__global__ void __launch_bounds__(256) k_gather(const unsigned short* __restrict__ mf,
    const unsigned short* __restrict__ mr,
    const int* __restrict__ start_in, const int* __restrict__ end_in, const int* __restrict__ list_in,
    const int* __restrict__ start_out, const int* __restrict__ end_out, const int* __restrict__ list_out,
    short* __restrict__ aggb){
  int n = blockIdx.x*4 + (threadIdx.x>>6);
  int l = threadIdx.x & 63;
  float4 acc = {0.f,0.f,0.f,0.f};
  int s0 = start_in[n], e0 = end_in[n];
  for (int i=s0; i<e0; i++){
    int e = list_in[i];
    ushort4 v = *(const ushort4*)&mf[(size_t)e*MSGD + 4*l];
    acc.x += bf2f(v.x); acc.y += bf2f(v.y); acc.z += bf2f(v.z); acc.w += bf2f(v.w);
  }
  int s1 = start_out[n], e1 = end_out[n];
  for (int i=s1; i<e1; i++){
    int e = list_out[i];
    ushort4 v = *(const ushort4*)&mr[(size_t)e*MSGD + 4*l];
    acc.x += bf2f(v.x); acc.y += bf2f(v.y); acc.z += bf2f(v.z); acc.w += bf2f(v.w);
  }
  s16x4 o;
  o[0]=f2bf(acc.x); o[1]=f2bf(acc.y); o[2]=f2bf(acc.z); o[3]=f2bf(acc.w);
  *(s16x4*)&aggb[(size_t)n*MSGD + 4*l] = o;
}

// ---------------- final message kernel: e_fin bf16 via LDS restage (canonical order) ----------------
__global__ void __launch_bounds__(256,2) k_msg_fin(const short* __restrict__ hb,
    const short* __restrict__ eeb, const int* __restrict__ from_idx, const int* __restrict__ to_idx,
    const short* __restrict__ w1f, const float* __restrict__ b1f,
    const short* __restrict__ w2f, const float* __restrict__ b2f,
    const short* __restrict__ w1r, const float* __restrict__ b1r,
    const short* __restrict__ w2r, const float* __restrict__ b2r,
    short* __restrict__ efb){
  __shared__ __align__(16) short Xs[64][328];
  __shared__ __align__(16) short Ys[64][264];
  __shared__ int sidx[64], didx[64];
  int t = threadIdx.x;
  int e0 = blockIdx.x*64;
  if (t < 64){ sidx[t]=from_idx[e0+t]; didx[t]=to_idx[e0+t]; }
  __syncthreads();
  for (int i=t; i<64*40; i+=256){
    int r = i/40, c8 = (i - r*40)*8;
    const short* src;
    if (c8 < 128)      src = hb + (size_t)sidx[r]*HD + c8;
    else if (c8 < 256) src = hb + (size_t)didx[r]*HD + (c8-128);
    else               src = eeb + (size_t)(e0+r)*EED + (c8-256);
    *(s16x8*)&Xs[r][c8] = *(const s16x8*)src;
  }
  __syncthreads();

  int wv = t>>6, l = t&63, lr = l&15, lq = l>>4;
  int cbase = wv*64;
  f32x4 fsv[4][4];

  for (int dir=0; dir<2; dir++){
    const s16x8* W1v = (const s16x8*)(dir ? w1r : w1f);
    const float* B1  = dir ? b1r : b1f;
    const s16x8* W2v = (const s16x8*)(dir ? w2r : w2f);
    const float* B2  = dir ? b2r : b2f;

    f32x4 acc[4][4];
    #pragma unroll
    for (int ct=0; ct<4; ct++){
      float bb = B1[cbase + ct*16 + lr];
      #pragma unroll
      for (int rt=0; rt<4; rt++) acc[rt][ct] = (f32x4){bb,bb,bb,bb};
    }
    {
      s16x8 a0[4], b0[4], b1[4];
      int sc0 = dir ? 4 : 0;
      #pragma unroll
      for (int rt=0;rt<4;rt++) a0[rt] = *(const s16x8*)&Xs[rt*16+lr][sc0*32 + lq*8];
      #pragma unroll
      for (int ct=0;ct<4;ct++) b0[ct] = W1v[(size_t)(0*16 + wv*4 + ct)*64 + l];
      #pragma unroll
      for (int ct=0;ct<4;ct++) b1[ct] = W1v[(size_t)(1*16 + wv*4 + ct)*64 + l];
      #pragma unroll
      for (int kt=0; kt<10; kt++){
        s16x8 an[4], bn[4];
        if (kt < 9){
          int sc = (dir && (kt+1)<8) ? ((kt+1)^4) : (kt+1);
          #pragma unroll
          for (int rt=0;rt<4;rt++) an[rt] = *(const s16x8*)&Xs[rt*16+lr][sc*32 + lq*8];
        }
        if (kt < 8){
          #pragma unroll
          for (int ct=0;ct<4;ct++) bn[ct] = W1v[(size_t)((kt+2)*16 + wv*4 + ct)*64 + l];
        }
        #pragma unroll
        for (int rt=0; rt<4; rt++)
          #pragma unroll
          for (int ct=0; ct<4; ct++)
            acc[rt][ct] = __builtin_amdgcn_mfma_f32_16x16x32_bf16(a0[rt], b0[ct], acc[rt][ct], 0,0,0);
        #pragma unroll
        for (int i=0;i<4;i++){ a0[i]=an[i]; b0[i]=b1[i]; b1[i]=bn[i]; }
      }
    }
    #pragma unroll
    for (int rt=0; rt<4; rt++)
      #pragma unroll
      for (int ct=0; ct<4; ct++)
        #pragma unroll
        for (int r=0; r<4; r++)
          Ys[rt*16 + lq*4 + r][cbase + ct*16 + lr] = f2bf(fmaxf(acc[rt][ct][r], 0.f));
    __syncthreads();

    f32x4 acc2[4][4];
    #pragma unroll
    for (int ct=0; ct<4; ct++){
      float bb = B2[cbase + ct*16 + lr];
      #pragma unroll
      for (int rt=0; rt<4; rt++) acc2[rt][ct] = (f32x4){bb,bb,bb,bb};
    }
    {
      s16x8 a0[4], b0[4], b1[4];
      #pragma unroll
      for (int rt=0;rt<4;rt++) a0[rt] = *(const s16x8*)&Ys[rt*16+lr][lq*8];
      #pragma unroll
      for (int ct=0;ct<4;ct++) b0[ct] = W2v[(size_t)(0*16 + wv*4 + ct)*64 + l];
      #pragma unroll
      for (int ct=0;ct<4;ct++) b1[ct] = W2v[(size_t)(1*16 + wv*4 + ct)*64 + l];
      #pragma unroll
      for (int kt=0; kt<8; kt++){
        s16x8 an[4], bn[4];
        if (kt < 7){
          #pragma unroll
          for (int rt=0;rt<4;rt++) an[rt] = *(const s16x8*)&Ys[rt*16+lr][(kt+1)*32 + lq*8];
        }
        if (kt < 6){
          #pragma unroll
          for (int ct=0;ct<4;ct++) bn[ct] = W2v[(size_t)((kt+2)*16 + wv*4 + ct)*64 + l];
        }
        #pragma unroll
        for (int rt=0; rt<4; rt++)
          #pragma unroll
          for (int ct=0; ct<4; ct++)
            acc2[rt][ct] = __builtin_amdgcn_mfma_f32_16x16x32_bf16(a0[rt], b0[ct], acc2[rt][ct], 0,0,0);
        #pragma unroll
        for (int i=0;i<4;i++){ a0[i]=an[i]; b0[i]=b1[i]; b1[i]=bn[i]; }
      }
    }

    if (dir==0){
      #pragma unroll
      for (int rt=0; rt<4; rt++)
        #pragma unroll
        for (int ct=0; ct<4; ct++) fsv[rt][ct] = acc2[rt][ct];
      __syncthreads();
    } else {
      __syncthreads();
      #pragma unroll
      for (int rt=0; rt<4; rt++)
        #pragma unroll
        for (int ct=0; ct<4; ct++)
          #pragma unroll
          for (int r=0; r<4; r++)
            Ys[rt*16 + lq*4 + r][cbase + ct*16 + lr] = f2bf(fsv[rt][ct][r] + acc2[rt][ct][r]);
      __syncthreads();
      short* dst = efb + (size_t)e0*MSGD;
      for (int i=t; i<64*32; i+=256){
        int row = i>>5, c8 = (i&31)*8;
        *(s16x8*)&dst[(size_t)row*MSGD + c8] = *(const s16x8*)&Ys[row][c8];
      }
    }
  }
}

// ---------------- GRU (aggb in permuted order; Wih packed to match) ----------------
__global__ void __launch_bounds__(256,2) k_gru(const float* __restrict__ h,
    const short* __restrict__ hb, const short* __restrict__ aggb,
    const short* __restrict__ wih_p, const float* __restrict__ bih,
    const short* __restrict__ whh_p, const float* __restrict__ bhh,
    float* __restrict__ hnew, short* __restrict__ hnewb){
  __shared__ __align__(16) short aggs[64][264];
  __shared__ __align__(16) short hs[64][136];
  int t = threadIdx.x;
  int n0 = blockIdx.x*64;
  for (int i=t; i<64*32; i+=256){
    int r = i>>5, c8 = (i&31)*8;
    *(s16x8*)&aggs[r][c8] = *(const s16x8*)&aggb[(size_t)(n0+r)*MSGD + c8];
  }
  for (int i=t; i<64*16; i+=256){
    int r = i>>4, c8 = (i&15)*8;
    *(s16x8*)&hs[r][c8] = *(const s16x8*)&hb[(size_t)(n0+r)*HD + c8];
  }
  __syncthreads();

  int wv = t>>6, l = t&63, lr = l&15, lq = l>>4;
  const s16x8* Wih_v = (const s16x8*)wih_p;
  const s16x8* Whh_v = (const s16x8*)whh_p;

  f32x4 gi[4][6], gh[4][6];
  #pragma unroll
  for (int ct=0; ct<6; ct++){
    int bcol = (ct>>1)*128 + wv*32 + (ct&1)*16 + lr;
    float bi = bih[bcol], bh = bhh[bcol];
    #pragma unroll
    for (int rt=0; rt<4; rt++){
      gi[rt][ct] = (f32x4){bi,bi,bi,bi};
      gh[rt][ct] = (f32x4){bh,bh,bh,bh};
    }
  }
  for (int kt=0; kt<8; kt++){
    s16x8 af[4], bfr[6];
    #pragma unroll
    for (int rt=0; rt<4; rt++) af[rt] = *(const s16x8*)&aggs[rt*16+lr][kt*32 + lq*8];
    #pragma unroll
    for (int ct=0; ct<6; ct++){
      int nt = (ct>>1)*8 + wv*2 + (ct&1);
      bfr[ct] = Wih_v[(size_t)(kt*24 + nt)*64 + l];
    }
    #pragma unroll
    for (int rt=0; rt<4; rt++)
      #pragma unroll
      for (int ct=0; ct<6; ct++)
        gi[rt][ct] = __builtin_amdgcn_mfma_f32_16x16x32_bf16(af[rt], bfr[ct], gi[rt][ct], 0,0,0);
  }
  for (int kt=0; kt<4; kt++){
    s16x8 af[4], bfr[6];
    #pragma unroll
    for (int rt=0; rt<4; rt++) af[rt] = *(const s16x8*)&hs[rt*16+lr][kt*32 + lq*8];
    #pragma unroll
    for (int ct=0; ct<6; ct++){
      int nt = (ct>>1)*8 + wv*2 + (ct&1);
      bfr[ct] = Whh_v[(size_t)(kt*24 + nt)*64 + l];
    }
    #pragma unroll
    for (int rt=0; rt<4; rt++)
      #pragma unroll
      for (int ct=0; ct<6; ct++)
        gh[rt][ct] = __builtin_amdgcn_mfma_f32_16x16x32_bf16(af[rt], bfr[ct], gh[rt][ct], 0,0,0);
  }
  #pragma unroll
  for (int rt=0; rt<4; rt++)
    #pragma unroll
    for (int j=0; j<2; j++)
      #pragma unroll
      for (int r=0; r<4; r++){
        int row = n0 + rt*16 + lq*4 + r;
        int col = wv*32 + j*16 + lr;
        float rr = 1.f/(1.f + __expf(-(gi[rt][j][r]   + gh[rt][j][r])));
        float zz = 1.f/(1.f + __expf(-(gi[rt][2+j][r] + gh[rt][2+j][r])));
        float gn = gi[rt][4+j][r] + rr*gh[rt][4+j][r];
        float nn = 1.f - 2.f/(__expf(2.f*gn) + 1.f);   // tanh
        float hold = h[(size_t)row*HD + col];
        float hv = (1.f - zz)*nn + zz*hold;
        hnew[(size_t)row*HD + col] = hv;
        hnewb[(size_t)row*HD + col] = f2bf(hv);
      }
}

// ---------------- SK transform, bf16 MFMA (bf16 e_fin input) ----------------
__global__ void __launch_bounds__(256,2) k_tall(const short* __restrict__ efb,
    const short* __restrict__ W1p, const float* __restrict__ b1,
    const short* __restrict__ W2p, const float* __restrict__ b2,
    float* __restrict__ tall){
  __shared__ __align__(16) short Xs[64][264];
  __shared__ __align__(16) short Ys[64][40];
  int t = threadIdx.x;
  int g = blockIdx.x>>2, r0 = (blockIdx.x&3)*64;
  for (int i=t; i<64*32; i+=256){
    int r = i>>5, c8 = (i&31)*8;
    int row = r0 + r;
    s16x8 v = (row < EPG) ? *(const s16x8*)&efb[((size_t)g*EPG + row)*MSGD + c8]
                          : (s16x8){0,0,0,0,0,0,0,0};
    *(s16x8*)&Xs[r][c8] = v;
  }
  __syncthreads();
  int wv = t>>6, l = t&63, lr = l&15, lq = l>>4;
  const s16x8* W1v = (const s16x8*)W1p;
  const s16x8* W2v = (const s16x8*)W2p;
  f32x4 acc[2];
  #pragma unroll
  for (int ct=0; ct<2; ct++){
    float bb = b1[ct*16 + lr];
    acc[ct] = (f32x4){bb,bb,bb,bb};
  }
  for (int kt=0; kt<8; kt++){
    s16x8 a = *(const s16x8*)&Xs[wv*16+lr][kt*32 + lq*8];
    #pragma unroll
    for (int ct=0; ct<2; ct++){
      s16x8 bfr = W1v[(size_t)(kt*2 + ct)*64 + l];
      acc[ct] = __builtin_amdgcn_mfma_f32_16x16x32_bf16(a, bfr, acc[ct], 0,0,0);
    }
  }
  #pragma unroll
  for (int ct=0; ct<2; ct++)
    #pragma unroll
    for (int r=0; r<4; r++)
      Ys[wv*16 + lq*4 + r][ct*16 + lr] = f2bf(fmaxf(acc[ct][r], 0.f));
  __syncthreads();
  f32x4 acc2[2];
  #pragma unroll
  for (int ct=0; ct<2; ct++){
    float bb = b2[ct*16 + lr];
    acc2[ct] = (f32x4){bb,bb,bb,bb};
  }
  {
    s16x8 a = *(const s16x8*)&Ys[wv*16+lr][lq*8];
    #pragma unroll
    for (int ct=0; ct<2; ct++){
      s16x8 bfr = W2v[(size_t)ct*64 + l];
      acc2[ct] = __builtin_amdgcn_mfma_f32_16x16x32_bf16(a, bfr, acc2[ct], 0,0,0);
    }
  }
  #pragma unroll
  for (int ct=0; ct<2; ct++)
    #pragma unroll
    for (int r=0; r<4; r++){
      int row = r0 + wv*16 + lq*4 + r;
      tall[((size_t)g*256 + row)*SKD + ct*16 + lr] = (row < EPG) ? acc2[ct][r] : 0.f;
    }
}

// ---------------- Sinkhorn fused with la-init; 4-row-group matmul ----------------
__global__ void __attribute__((amdgpu_waves_per_eu(4,4))) __launch_bounds__(1024)
k_sinkhorn(const float* __restrict__ tall, short* __restrict__ plan){
  __shared__ float tqs[256*32];
  __shared__ float tcsT[32*257];
  __shared__ float cv[256];
  __shared__ float psm[16][256];
  int p = blockIdx.x, t = threadIdx.x;
  int w = t>>6, l = t&63;
  int rbase = w*16;
  const float* tq = tall + (size_t)(2*p)*8192;
  const float* tc = tall + (size_t)(2*p+1)*8192;
  for (int i=t; i<8192; i+=1024){
    tqs[i] = tq[i];
    tcsT[(i&31)*257 + (i>>5)] = tc[i];
  }
  __syncthreads();
  float4 E[16];
  #pragma unroll
  for (int kg=0; kg<4; kg++){
    float4 a0_ = {0.f,0.f,0.f,0.f}, a1_ = a0_, a2_ = a0_, a3_ = a0_;
    for (int kk=0; kk<32; kk+=4){
      float4 c0 = *(const float4*)&tcsT[(kk+0)*257 + 4*l];
      float4 c1 = *(const float4*)&tcsT[(kk+1)*257 + 4*l];
      float4 c2 = *(const float4*)&tcsT[(kk+2)*257 + 4*l];
      float4 c3 = *(const float4*)&tcsT[(kk+3)*257 + 4*l];
      float4 q0 = *(const float4*)&tqs[(rbase+kg*4+0)*32 + kk];
      float4 q1 = *(const float4*)&tqs[(rbase+kg*4+1)*32 + kk];
      float4 q2 = *(const float4*)&tqs[(rbase+kg*4+2)*32 + kk];
      float4 q3 = *(const float4*)&tqs[(rbase+kg*4+3)*32 + kk];
      a0_.x = fmaf(q0.x,c0.x, fmaf(q0.y,c1.x, fmaf(q0.z,c2.x, fmaf(q0.w,c3.x, a0_.x))));
      a0_.y = fmaf(q0.x,c0.y, fmaf(q0.y,c1.y, fmaf(q0.z,c2.y, fmaf(q0.w,c3.y, a0_.y))));
      a0_.z = fmaf(q0.x,c0.z, fmaf(q0.y,c1.z, fmaf(q0.z,c2.z, fmaf(q0.w,c3.z, a0_.z))));
      a0_.w = fmaf(q0.x,c0.w, fmaf(q0.y,c1.w, fmaf(q0.z,c2.w, fmaf(q0.w,c3.w, a0_.w))));
      a1_.x = fmaf(q1.x,c0.x, fmaf(q1.y,c1.x, fmaf(q1.z,c2.x, fmaf(q1.w,c3.x, a1_.x))));
      a1_.y = fmaf(q1.x,c0.y, fmaf(q1.y,c1.y, fmaf(q1.z,c2.y, fmaf(q1.w,c3.y, a1_.y))));
      a1_.z = fmaf(q1.x,c0.z, fmaf(q1.y,c1.z, fmaf(q1.z,c2.z, fmaf(q1.w,c3.z, a1_.z))));
      a1_.w = fmaf(q1.x,c0.w, fmaf(q1.y,c1.w, fmaf(q1.z,c2.w, fmaf(q1.w,c3.w, a1_.w))));
      a2_.x = fmaf(q2.x,c0.x, fmaf(q2.y,c1.x, fmaf(q2.z,c2.x, fmaf(q2.w,c3.x, a2_.x))));
      a2_.y = fmaf(q2.x,c0.y, fmaf(q2.y,c1.y, fmaf(q2.z,c2.y, fmaf(q2.w,c3.y, a2_.y))));
      a2_.z = fmaf(q2.x,c0.z, fmaf(q2.y,c1.z, fmaf(q2.z,c2.z, fmaf(q2.w,c3.z, a2_.z))));
      a2_.w = fmaf(q2.x,c0.w, fmaf(q2.y,c1.w, fmaf(q2.z,c2.w, fmaf(q2.w,c3.w, a2_.w))));
      a3_.x = fmaf(q3.x,c0.x, fmaf(q3.y,c1.x, fmaf(q3.z,c2.x, fmaf(q3.w,c3.x, a3_.x))));
      a3_.y = fmaf(q3.x,c0.y, fmaf(q3.y,c1.y, fmaf(q3.z,c2.y, fmaf(q3.w,c3.y, a3_.y))));
      a3_.z = fmaf(q3.x,c0.z, fmaf(q3.y,c1.z, fmaf(q3.z,c2.z, fmaf(q3.w,c3.z, a3_.z))));
      a3_.w = fmaf(q3.x,c0.w, fmaf(q3.y,c1.w, fmaf(q3.z,c2.w, fmaf(q3.w,c3.w, a3_.w))));
    }
    #pragma unroll
    for (int j=0; j<4; j++){
      float4 a = (j==0)?a0_:(j==1)?a1_:(j==2)?a2_:a3_;
      a.x *= 10.f; a.y *= 10.f; a.z *= 10.f; a.w *= 10.f;
      float m = fmaxf(fmaxf(a.x,a.y), fmaxf(a.z,a.w));
      #pragma unroll
      for (int off=32; off; off>>=1) m = fmaxf(m, __shfl_xor(m, off));
      float s = __expf(a.x-m)+__expf(a.y-m)+__expf(a.z-m)+__expf(a.w-m);
      #pragma unroll
      for (int off=32; off; off>>=1) s += __shfl_xor(s, off);
      float r = m + __logf(s);
      E[kg*4+j].x = __expf(a.x - r); E[kg*4+j].y = __expf(a.y - r);
      E[kg*4+j].z = __expf(a.z - r); E[kg*4+j].w = __expf(a.w - r);
    }
  }

  for (int it=0; it<20; it++){
    float4 sm = {0.f,0.f,0.f,0.f};
    #pragma unroll
    for (int k=0;k<16;k++){
      sm.x += E[k].x; sm.y += E[k].y; sm.z += E[k].z; sm.w += E[k].w;
    }
    *(float4*)&psm[w][4*l] = sm;
    __syncthreads();
    if (t < 256){
      float s = psm[0][t];
      #pragma unroll
      for (int ww=1; ww<16; ww++) s += psm[ww][t];
      cv[t] = frcp(s);
    }
    __syncthreads();
    float4 ic = *(const float4*)&cv[4*l];
    #pragma unroll
    for (int k=0;k<16;k++){
      E[k].x *= ic.x; E[k].y *= ic.y; E[k].z *= ic.z; E[k].w *= ic.w;
    }
    if (it < 19){
      #pragma unroll
      for (int k=0;k<16;k++){
        float s = E[k].x + E[k].y + E[k].z + E[k].w;
        #pragma unroll
        for (int off=32; off; off>>=1) s += __shfl_xor(s, off);
        float inv = frcp(s);
        E[k].x *= inv; E[k].y *= inv; E[k].z *= inv; E[k].w *= inv;
      }
    }
  }
  short* P = plan + (size_t)p*65536;
  #pragma unroll
  for (int k=0;k<16;k++){
    s16x4 o;
    o[0]=f2bf(E[k].x); o[1]=f2bf(E[k].y); o[2]=f2bf(E[k].z); o[3]=f2bf(E[k].w);
    *(s16x4*)&P[(size_t)(rbase+k)*256 + 4*l] = o;
  }
}

// ---------------- loss: bf16 plan @ bf16 c, fused relu-reduce ----------------
__global__ void __launch_bounds__(256,2) k_loss(const short* __restrict__ plan,
    const short* __restrict__ efb, float* __restrict__ out){
  __shared__ __align__(16) short Ps[128][40];
  __shared__ __align__(16) short Cs[256][40];
  __shared__ float red[4];
  int t = threadIdx.x;
  int b = blockIdx.x, p = b>>1, rh = b&1;
  int i0 = rh*128;
  int wv = t>>6, l = t&63, lr = l&15, lq = l>>4;
  const short* Pb = plan + (size_t)p*65536;
  const unsigned short* C = (const unsigned short*)(efb + (size_t)(2*p+1)*EPG*MSGD);
  const unsigned short* Q = (const unsigned short*)(efb + (size_t)(2*p)*EPG*MSGD);

  f32x4 acc[2][16];
  #pragma unroll
  for (int rt=0;rt<2;rt++)
    #pragma unroll
    for (int ct=0;ct<16;ct++) acc[rt][ct] = (f32x4){0.f,0.f,0.f,0.f};

  for (int kt=0; kt<8; kt++){
    __syncthreads();
    for (int i=t; i<128*4; i+=256){
      int r = i>>2, c8 = (i&3)*8;
      *(s16x8*)&Ps[r][c8] = *(const s16x8*)&Pb[(size_t)(i0+r)*256 + kt*32 + c8];
    }
    for (int i=t; i<32*64; i+=256){
      int k = i>>6, c4 = (i&63)*4;
      int j = kt*32 + k;
      ushort4 v = (j < EPG) ? *(const ushort4*)&C[(size_t)j*256 + c4] : (ushort4){0,0,0,0};
      Cs[c4+0][k]=(short)v.x; Cs[c4+1][k]=(short)v.y; Cs[c4+2][k]=(short)v.z; Cs[c4+3][k]=(short)v.w;
    }
    __syncthreads();
    s16x8 a0 = *(const s16x8*)&Ps[wv*32      + lr][lq*8];
    s16x8 a1 = *(const s16x8*)&Ps[wv*32 + 16 + lr][lq*8];
    #pragma unroll
    for (int ct=0; ct<16; ct++){
      s16x8 bfr = *(const s16x8*)&Cs[ct*16+lr][lq*8];
      acc[0][ct] = __builtin_amdgcn_mfma_f32_16x16x32_bf16(a0, bfr, acc[0][ct], 0,0,0);
      acc[1][ct] = __builtin_amdgcn_mfma_f32_16x16x32_bf16(a1, bfr, acc[1][ct], 0,0,0);
    }
  }
  float s = 0.f;
  #pragma unroll
  for (int rt=0; rt<2; rt++)
    #pragma unroll
    for (int ct=0; ct<16; ct++)
      #pragma unroll
      for (int r=0; r<4; r++){
        int row = i0 + wv*32 + rt*16 + lq*4 + r;
        int col = ct*16 + lr;
        float q = (row < EPG) ? bf2f(Q[(size_t)row*256 + col]) : 0.f;
        s += fmaxf(q - acc[rt][ct][r], 0.f);
      }
  #pragma unroll
  for (int off=32; off; off>>=1) s += __shfl_xor(s, off);
  if (l==0) red[wv] = s;
  __syncthreads();
  if (t==0) atomicAdd(&out[p], -(red[0]+red[1]+red[2]+red[3]));
}

// ---------------- launch ----------------
extern "C" void kernel_launch(void* const* d_in, const int* in_sizes, int n_in,
                              void* d_out, int out_size, void* d_ws, size_t ws_size,
                              hipStream_t stream){
  const float* nf   = (const float*)d_in[0];
  const float* ef   = (const float*)d_in[1];
  const int*   fidx = (const int*)d_in[2];
  const int*   tidx = (const int*)d_in[3];
  const float* enw  = (const float*)d_in[4];
  const float* enb  = (const float*)d_in[5];
  const float* eew  = (const float*)d_in[6];
  const float* eeb_w= (const float*)d_in[7];
  const float* mw1  = (const float*)d_in[8];
  const float* mb1  = (const float*)d_in[9];
  const float* mw2  = (const float*)d_in[10];
  const float* mb2  = (const float*)d_in[11];
  const float* rw1  = (const float*)d_in[12];
  const float* rb1  = (const float*)d_in[13];
  const float* rw2  = (const float*)d_in[14];
  const float* rb2  = (const float*)d_in[15];
  const float* wih  = (const float*)d_in[16];
  const float* bih  = (const float*)d_in[17];
  const float* whh  = (const float*)d_in[18];
  const float* bhh  = (const float*)d_in[19];
  const float* skw1 = (const float*)d_in[20];
  const float* skb1 = (const float*)d_in[21];
  const float* skw2 = (const float*)d_in[22];
  const float* skb2 = (const float*)d_in[23];
  float* out = (float*)d_out;

  float* ws = (float*)d_ws;
  float* h_a   = ws;                               // NN*HD f
  float* h_b   = h_a + (size_t)NN*HD;              // NN*HD f
  short* hb_a  = (short*)(h_b + (size_t)NN*HD);    // NN*HD sh
  short* hb_b  = hb_a + (size_t)NN*HD;             // NN*HD sh
  short* ee_b  = hb_b + (size_t)NN*HD;             // NE*EED sh
  short* mf    = ee_b + (size_t)NE*EED;            // NE*MSGD sh
  short* mr    = mf + (size_t)NE*MSGD;             // NE*MSGD sh
  short* e_finb = mf;                              // alias (mf/mr dead after loop)
  float* t_all = (float*)(mr + (size_t)NE*MSGD);   // NG*256*SKD f
  float* la    = t_all + (size_t)NG*256*SKD;       // plan/agg/skw region

  short* w1f_p = (short*)t_all;
  short* w1r_p = w1f_p + 320*256;
  short* w2f_p = w1r_p + 320*256;
  short* w2r_p = w2f_p + 256*256;
  short* wih_p = w2r_p + 256*256;
  short* whh_p = wih_p + 256*384;
  int*   csr   = (int*)(t_all + 221184);
  int* cur_in    = csr;
  int* cur_out   = cur_in  + NN;
  int* start_in  = cur_out + NN;
  int* start_out = start_in + NN;
  int* list_in   = start_out + NN;
  int* list_out  = list_in + NE;

  short* aggb   = (short*)la;                      // NN*MSGD sh (loop phase)
  short* plan_s = (short*)la;                      // NP*65536 sh (after loop)
  short* skw1_p = (short*)(la + 9000000);
  short* skw2_p = skw1_p + 256*32;

  k_pack_all<<<221, 256, 0, stream>>>(mw1, rw1, mw2, rw2, wih, whh, skw1, skw2,
      w1f_p, w1r_p, w2f_p, w2r_p, wih_p, whh_p, skw1_p, skw2_p);

  k_enc_node<<<NN/2, 256, 0, stream>>>(nf, enw, enb, h_a, hb_a);
  k_enc_edge<<<NE/4, 256, 0, stream>>>(ef, eew, eeb_w, ee_b);

  hipMemsetAsync(csr, 0, (size_t)2*NN*sizeof(int), stream);
  k_csr_count<<<NE/256, 256, 0, stream>>>(fidx, tidx, cur_in, cur_out);
  k_csr_scan<<<NG, 64, 0, stream>>>(cur_in, start_in, cur_out, start_out);
  k_csr_fill<<<NE/256, 256, 0, stream>>>(fidx, tidx, cur_in, cur_out, list_in, list_out);

  float* hc = h_a; float* hn = h_b;
  short* hbc = hb_a; short* hbn = hb_b;
  for (int step=0; step<5; step++){
    k_msg_both<<<NE/64, 256, 0, stream>>>(hbc, ee_b, fidx, tidx,
        w1f_p, mb1, w2f_p, mb2, w1r_p, rb1, w2r_p, rb2, mf, mr);
    k_gather<<<NN/4, 256, 0, stream>>>((const unsigned short*)mf, (const unsigned short*)mr,
        start_in, cur_in, list_in, start_out, cur_out, list_out, aggb);
    k_gru<<<NN/64, 256, 0, stream>>>(hc, hbc, aggb, wih_p, bih, whh_p, bhh, hn, hbn);
    float* tmp = hc; hc = hn; hn = tmp;
    short* tmb = hbc; hbc = hbn; hbn = tmb;
  }
  k_msg_fin<<<NE/64, 256, 0, stream>>>(hbc, ee_b, fidx, tidx,
      w1f_p, mb1, w2f_p, mb2, w1r_p, rb1, w2r_p, rb2, e_finb);

  k_tall<<<NG*4, 256, 0, stream>>>(e_finb, skw1_p, skb1, skw2_p, skb2, t_all);
  k_sinkhorn<<<NP, 1024, 0, stream>>>(t_all, plan_s);

  hipMemsetAsync(out, 0, (size_t)NP*sizeof(float), stream);
  k_loss<<<NP*2, 256, 0, stream>>>(plan_s, e_finb, out);
}

// Round 18
// 1070.788 us; speedup vs baseline: 1.0539x; 1.0539x over previous
//
#include <hip/hip_runtime.h>
#include <math.h>

typedef __attribute__((ext_vector_type(4))) float f32x4;
typedef __attribute__((ext_vector_type(8))) short s16x8;
typedef __attribute__((ext_vector_type(4))) short s16x4;

#define NN 32768      // nodes
#define NE 102400     // edges
#define HD 128        // H
#define EED 64        // edge enc dim
#define MSGD 256
#define NG 512        // graphs
#define EPG 200       // edges per graph
#define NP 256        // pairs
#define SKD 32

__device__ inline short f2bf(float x){
  union{float f; unsigned u;} z; z.f=x;
  unsigned r = (z.u + 0x7fffu + ((z.u>>16)&1u)) >> 16;
  return (short)r;
}
__device__ inline float bf2f(unsigned short u){
  union{unsigned u; float f;} z; z.u = ((unsigned)u)<<16; return z.f;
}
__device__ inline float frcp(float x){
  float r; asm("v_rcp_f32 %0, %1" : "=v"(r) : "v"(x)); return r;
}

// ---------------- node encoder: h (f32) + hb (bf16) ----------------
__global__ void __launch_bounds__(256) k_enc_node(const float* __restrict__ nf,
    const float* __restrict__ W, const float* __restrict__ b,
    float* __restrict__ h, short* __restrict__ hb){
  __shared__ float Ws[16*128];
  int t = threadIdx.x;
  for (int i=t;i<16*128;i+=256) Ws[i]=W[i];
  __syncthreads();
  int node = blockIdx.x*2 + (t>>7);
  int f = t & 127;
  const float* x = nf + node*16;
  float acc = b[f];
  #pragma unroll
  for (int k=0;k<16;k++) acc = fmaf(x[k], Ws[k*128+f], acc);
  h[node*HD+f] = acc;
  hb[node*HD+f] = f2bf(acc);
}

// ---------------- edge encoder: bf16 output ----------------
__global__ void __launch_bounds__(256) k_enc_edge(const float* __restrict__ ef,
    const float* __restrict__ W, const float* __restrict__ b, short* __restrict__ eeb){
  __shared__ float Ws[16*64];
  int t = threadIdx.x;
  for (int i=t;i<16*64;i+=256) Ws[i]=W[i];
  __syncthreads();
  int edge = blockIdx.x*4 + (t>>6);
  int f = t & 63;
  const float* x = ef + edge*16;
  float acc = b[f];
  #pragma unroll
  for (int k=0;k<16;k++) acc = fmaf(x[k], Ws[k*64+f], acc);
  eeb[edge*EED+f] = f2bf(acc);
}

// ---------------- all weight packs in one launch (canonical order) ----------------
__global__ void __launch_bounds__(256) k_pack_all(
    const float* __restrict__ mw1, const float* __restrict__ rw1,
    const float* __restrict__ mw2, const float* __restrict__ rw2,
    const float* __restrict__ wih, const float* __restrict__ whh,
    const float* __restrict__ skw1, const float* __restrict__ skw2,
    short* __restrict__ w1f_p, short* __restrict__ w1r_p,
    short* __restrict__ w2f_p, short* __restrict__ w2r_p,
    short* __restrict__ wih_p, short* __restrict__ whh_p,
    short* __restrict__ skw1_p, short* __restrict__ skw2_p){
  int b = blockIdx.x;
  const float* W; short* dst; int K, N;
  if      (b < 40) { W=mw1;  dst=w1f_p;  K=320; N=256; }
  else if (b < 80) { W=rw1;  dst=w1r_p;  K=320; N=256; b-=40; }
  else if (b < 112){ W=mw2;  dst=w2f_p;  K=256; N=256; b-=80; }
  else if (b < 144){ W=rw2;  dst=w2r_p;  K=256; N=256; b-=112; }
  else if (b < 192){ W=wih;  dst=wih_p;  K=256; N=384; b-=144; }
  else if (b < 216){ W=whh;  dst=whh_p;  K=128; N=384; b-=192; }
  else if (b < 220){ W=skw1; dst=skw1_p; K=256; N=32;  b-=216; }
  else             { W=skw2; dst=skw2_p; K=32;  N=32;  b-=220; }
  int NT = N >> 4;
  int i = b*256 + (int)threadIdx.x;
  if (i >= (K/32)*NT*64) return;
  int l = i & 63, tile = i >> 6;
  int nt = tile % NT, kt = tile / NT;
  int lr = l & 15, lq = l >> 4;
  s16x8 v;
  #pragma unroll
  for (int j=0;j<8;j++)
    v[j] = f2bf(W[(size_t)(kt*32 + lq*8 + j)*N + nt*16 + lr]);
  *((s16x8*)dst + i) = v;
}

// ---------------- CSR build ----------------
__global__ void __launch_bounds__(256) k_csr_count(const int* __restrict__ fidx,
    const int* __restrict__ tidx, int* __restrict__ cur_in, int* __restrict__ cur_out){
  int e = blockIdx.x*256 + threadIdx.x;
  if (e >= NE) return;
  atomicAdd(&cur_in[tidx[e]], 1);
  atomicAdd(&cur_out[fidx[e]], 1);
}
__global__ void k_csr_scan(int* __restrict__ cur_in, int* __restrict__ start_in,
    int* __restrict__ cur_out, int* __restrict__ start_out){
  if (threadIdx.x) return;
  int g = blockIdx.x;
  int n0 = g*64, base = g*EPG;
  int run = base;
  for (int i=0;i<64;i++){ int c=cur_in[n0+i]; start_in[n0+i]=run; cur_in[n0+i]=run; run+=c; }
  run = base;
  for (int i=0;i<64;i++){ int c=cur_out[n0+i]; start_out[n0+i]=run; cur_out[n0+i]=run; run+=c; }
}
__global__ void __launch_bounds__(256) k_csr_fill(const int* __restrict__ fidx,
    const int* __restrict__ tidx, int* __restrict__ cur_in, int* __restrict__ cur_out,
    int* __restrict__ list_in, int* __restrict__ list_out){
  int e = blockIdx.x*256 + threadIdx.x;
  if (e >= NE) return;
  int p1 = atomicAdd(&cur_in[tidx[e]], 1);  list_in[p1] = e;
  int p2 = atomicAdd(&cur_out[fidx[e]], 1); list_out[p2] = e;
}

// ---------------- message MLPs (fwd+rev), bf16-at-rest inputs (best R14/R16 structure) ----------------
__global__ void __launch_bounds__(256,2) k_msg_both(const short* __restrict__ hb,
    const short* __restrict__ eeb, const int* __restrict__ from_idx, const int* __restrict__ to_idx,
    const short* __restrict__ w1f, const float* __restrict__ b1f,
    const short* __restrict__ w2f, const float* __restrict__ b2f,
    const short* __restrict__ w1r, const float* __restrict__ b1r,
    const short* __restrict__ w2r, const float* __restrict__ b2r,
    short* __restrict__ mf, short* __restrict__ mr){
  __shared__ __align__(16) short Xs[64][328];
  __shared__ __align__(16) short Ys[64][264];
  __shared__ int sidx[64], didx[64];
  int t = threadIdx.x;
  int e0 = blockIdx.x*64;
  if (t < 64){ sidx[t]=from_idx[e0+t]; didx[t]=to_idx[e0+t]; }
  __syncthreads();
  for (int i=t; i<64*40; i+=256){
    int r = i/40, c8 = (i - r*40)*8;
    const short* src;
    if (c8 < 128)      src = hb + (size_t)sidx[r]*HD + c8;
    else if (c8 < 256) src = hb + (size_t)didx[r]*HD + (c8-128);
    else               src = eeb + (size_t)(e0+r)*EED + (c8-256);
    *(s16x8*)&Xs[r][c8] = *(const s16x8*)src;
  }
  __syncthreads();

  int wv = t>>6, l = t&63, lr = l&15, lq = l>>4;
  int cbase = wv*64;

  for (int dir=0; dir<2; dir++){
    const s16x8* W1v = (const s16x8*)(dir ? w1r : w1f);
    const float* B1  = dir ? b1r : b1f;
    const s16x8* W2v = (const s16x8*)(dir ? w2r : w2f);
    const float* B2  = dir ? b2r : b2f;

    f32x4 acc[4][4];
    #pragma unroll
    for (int ct=0; ct<4; ct++){
      float bb = B1[cbase + ct*16 + lr];
      #pragma unroll
      for (int rt=0; rt<4; rt++) acc[rt][ct] = (f32x4){bb,bb,bb,bb};
    }
    {
      s16x8 a0[4], b0[4], b1[4];
      int sc0 = dir ? 4 : 0;
      #pragma unroll
      for (int rt=0;rt<4;rt++) a0[rt] = *(const s16x8*)&Xs[rt*16+lr][sc0*32 + lq*8];
      #pragma unroll
      for (int ct=0;ct<4;ct++) b0[ct] = W1v[(size_t)(0*16 + wv*4 + ct)*64 + l];
      #pragma unroll
      for (int ct=0;ct<4;ct++) b1[ct] = W1v[(size_t)(1*16 + wv*4 + ct)*64 + l];
      #pragma unroll
      for (int kt=0; kt<10; kt++){
        s16x8 an[4], bn[4];
        if (kt < 9){
          int sc = (dir && (kt+1)<8) ? ((kt+1)^4) : (kt+1);
          #pragma unroll
          for (int rt=0;rt<4;rt++) an[rt] = *(const s16x8*)&Xs[rt*16+lr][sc*32 + lq*8];
        }
        if (kt < 8){
          #pragma unroll
          for (int ct=0;ct<4;ct++) bn[ct] = W1v[(size_t)((kt+2)*16 + wv*4 + ct)*64 + l];
        }
        #pragma unroll
        for (int rt=0; rt<4; rt++)
          #pragma unroll
          for (int ct=0; ct<4; ct++)
            acc[rt][ct] = __builtin_amdgcn_mfma_f32_16x16x32_bf16(a0[rt], b0[ct], acc[rt][ct], 0,0,0);
        #pragma unroll
        for (int i=0;i<4;i++){ a0[i]=an[i]; b0[i]=b1[i]; b1[i]=bn[i]; }
      }
    }
    #pragma unroll
    for (int rt=0; rt<4; rt++)
      #pragma unroll
      for (int ct=0; ct<4; ct++)
        #pragma unroll
        for (int r=0; r<4; r++)
          Ys[rt*16 + lq*4 + r][cbase + ct*16 + lr] = f2bf(fmaxf(acc[rt][ct][r], 0.f));
    __syncthreads();

    f32x4 acc2[4][4];
    #pragma unroll
    for (int ct=0; ct<4; ct++){
      float bb = B2[cbase + ct*16 + lr];
      #pragma unroll
      for (int rt=0; rt<4; rt++) acc2[rt][ct] = (f32x4){bb,bb,bb,bb};
    }
    {
      s16x8 a0[4], b0[4], b1[4];
      #pragma unroll
      for (int rt=0;rt<4;rt++) a0[rt] = *(const s16x8*)&Ys[rt*16+lr][lq*8];
      #pragma unroll
      for (int ct=0;ct<4;ct++) b0[ct] = W2v[(size_t)(0*16 + wv*4 + ct)*64 + l];
      #pragma unroll
      for (int ct=0;ct<4;ct++) b1[ct] = W2v[(size_t)(1*16 + wv*4 + ct)*64 + l];
      #pragma unroll
      for (int kt=0; kt<8; kt++){
        s16x8 an[4], bn[4];
        if (kt < 7){
          #pragma unroll
          for (int rt=0;rt<4;rt++) an[rt] = *(const s16x8*)&Ys[rt*16+lr][(kt+1)*32 + lq*8];
        }
        if (kt < 6){
          #pragma unroll
          for (int ct=0;ct<4;ct++) bn[ct] = W2v[(size_t)((kt+2)*16 + wv*4 + ct)*64 + l];
        }
        #pragma unroll
        for (int rt=0; rt<4; rt++)
          #pragma unroll
          for (int ct=0; ct<4; ct++)
            acc2[rt][ct] = __builtin_amdgcn_mfma_f32_16x16x32_bf16(a0[rt], b0[ct], acc2[rt][ct], 0,0,0);
        #pragma unroll
        for (int i=0;i<4;i++){ a0[i]=an[i]; b0[i]=b1[i]; b1[i]=bn[i]; }
      }
    }
    __syncthreads();
    #pragma unroll
    for (int rt=0; rt<4; rt++)
      #pragma unroll
      for (int ct=0; ct<4; ct++)
        #pragma unroll
        for (int r=0; r<4; r++)
          Ys[rt*16 + lq*4 + r][cbase + ct*16 + lr] = f2bf(acc2[rt][ct][r]);
    __syncthreads();
    {
      short* dst = (dir ? mr : mf) + (size_t)e0*MSGD;
      for (int i=t; i<64*32; i+=256){
        int row = i>>5, c8 = (i&31)*8;
        *(s16x8*)&dst[(size_t)row*MSGD + c8] = *(const s16x8*)&Ys[row][c8];
      }
    }
    __syncthreads();
  }
}

// ---------------- gather: aggb[n] (bf16) = sum_in mf + sum_out mr ----------------
__global__ void __launch_bounds__(256) k_gather(const unsigned short* __restrict__ mf,
    const unsigned short* __restrict__ mr,
    const int* __restrict__ start_in, const int* __restrict__ end_in, const int* __restrict__ list_in,
    const int* __restrict__ start_out, const int* __restrict__ end_out, const int* __restrict__ list_out,
    short* __restrict__ aggb){
  int n = blockIdx.x*4 + (threadIdx.x>>6);
  int l = threadIdx.x & 63;
  float4 acc = {0.f,0.f,0.f,0.f};
  int s0 = start_in[n], e0 = end_in[n];
  for (int i=s0; i<e0; i++){
    int e = list_in[i];
    ushort4 v = *(const ushort4*)&mf[(size_t)e*MSGD + 4*l];
    acc.x += bf2f(v.x); acc.y += bf2f(v.y); acc.z += bf2f(v.z); acc.w += bf2f(v.w);
  }
  int s1 = start_out[n], e1 = end_out[n];
  for (int i=s1; i<e1; i++){
    int e = list_out[i];
    ushort4 v = *(const ushort4*)&mr[(size_t)e*MSGD + 4*l];
    acc.x += bf2f(v.x); acc.y += bf2f(v.y); acc.z += bf2f(v.z); acc.w += bf2f(v.w);
  }
  s16x4 o;
  o[0]=f2bf(acc.x); o[1]=f2bf(acc.y); o[2]=f2bf(acc.z); o[3]=f2bf(acc.w);
  *(s16x4*)&aggb[(size_t)n*MSGD + 4*l] = o;
}

// ---------------- final message kernel: e_fin bf16 via LDS restage ----------------
__global__ void __launch_bounds__(256,2) k_msg_fin(const short* __restrict__ hb,
    const short* __restrict__ eeb, const int* __restrict__ from_idx, const int* __restrict__ to_idx,
    const short* __restrict__ w1f, const float* __restrict__ b1f,
    const short* __restrict__ w2f, const float* __restrict__ b2f,
    const short* __restrict__ w1r, const float* __restrict__ b1r,
    const short* __restrict__ w2r, const float* __restrict__ b2r,
    short* __restrict__ efb){
  __shared__ __align__(16) short Xs[64][328];
  __shared__ __align__(16) short Ys[64][264];
  __shared__ int sidx[64], didx[64];
  int t = threadIdx.x;
  int e0 = blockIdx.x*64;
  if (t < 64){ sidx[t]=from_idx[e0+t]; didx[t]=to_idx[e0+t]; }
  __syncthreads();
  for (int i=t; i<64*40; i+=256){
    int r = i/40, c8 = (i - r*40)*8;
    const short* src;
    if (c8 < 128)      src = hb + (size_t)sidx[r]*HD + c8;
    else if (c8 < 256) src = hb + (size_t)didx[r]*HD + (c8-128);
    else               src = eeb + (size_t)(e0+r)*EED + (c8-256);
    *(s16x8*)&Xs[r][c8] = *(const s16x8*)src;
  }
  __syncthreads();

  int wv = t>>6, l = t&63, lr = l&15, lq = l>>4;
  int cbase = wv*64;
  f32x4 fsv[4][4];

  for (int dir=0; dir<2; dir++){
    const s16x8* W1v = (const s16x8*)(dir ? w1r : w1f);
    const float* B1  = dir ? b1r : b1f;
    const s16x8* W2v = (const s16x8*)(dir ? w2r : w2f);
    const float* B2  = dir ? b2r : b2f;

    f32x4 acc[4][4];
    #pragma unroll
    for (int ct=0; ct<4; ct++){
      float bb = B1[cbase + ct*16 + lr];
      #pragma unroll
      for (int rt=0; rt<4; rt++) acc[rt][ct] = (f32x4){bb,bb,bb,bb};
    }
    {
      s16x8 a0[4], b0[4], b1[4];
      int sc0 = dir ? 4 : 0;
      #pragma unroll
      for (int rt=0;rt<4;rt++) a0[rt] = *(const s16x8*)&Xs[rt*16+lr][sc0*32 + lq*8];
      #pragma unroll
      for (int ct=0;ct<4;ct++) b0[ct] = W1v[(size_t)(0*16 + wv*4 + ct)*64 + l];
      #pragma unroll
      for (int ct=0;ct<4;ct++) b1[ct] = W1v[(size_t)(1*16 + wv*4 + ct)*64 + l];
      #pragma unroll
      for (int kt=0; kt<10; kt++){
        s16x8 an[4], bn[4];
        if (kt < 9){
          int sc = (dir && (kt+1)<8) ? ((kt+1)^4) : (kt+1);
          #pragma unroll
          for (int rt=0;rt<4;rt++) an[rt] = *(const s16x8*)&Xs[rt*16+lr][sc*32 + lq*8];
        }
        if (kt < 8){
          #pragma unroll
          for (int ct=0;ct<4;ct++) bn[ct] = W1v[(size_t)((kt+2)*16 + wv*4 + ct)*64 + l];
        }
        #pragma unroll
        for (int rt=0; rt<4; rt++)
          #pragma unroll
          for (int ct=0; ct<4; ct++)
            acc[rt][ct] = __builtin_amdgcn_mfma_f32_16x16x32_bf16(a0[rt], b0[ct], acc[rt][ct], 0,0,0);
        #pragma unroll
        for (int i=0;i<4;i++){ a0[i]=an[i]; b0[i]=b1[i]; b1[i]=bn[i]; }
      }
    }
    #pragma unroll
    for (int rt=0; rt<4; rt++)
      #pragma unroll
      for (int ct=0; ct<4; ct++)
        #pragma unroll
        for (int r=0; r<4; r++)
          Ys[rt*16 + lq*4 + r][cbase + ct*16 + lr] = f2bf(fmaxf(acc[rt][ct][r], 0.f));
    __syncthreads();

    f32x4 acc2[4][4];
    #pragma unroll
    for (int ct=0; ct<4; ct++){
      float bb = B2[cbase + ct*16 + lr];
      #pragma unroll
      for (int rt=0; rt<4; rt++) acc2[rt][ct] = (f32x4){bb,bb,bb,bb};
    }
    {
      s16x8 a0[4], b0[4], b1[4];
      #pragma unroll
      for (int rt=0;rt<4;rt++) a0[rt] = *(const s16x8*)&Ys[rt*16+lr][lq*8];
      #pragma unroll
      for (int ct=0;ct<4;ct++) b0[ct] = W2v[(size_t)(0*16 + wv*4 + ct)*64 + l];
      #pragma unroll
      for (int ct=0;ct<4;ct++) b1[ct] = W2v[(size_t)(1*16 + wv*4 + ct)*64 + l];
      #pragma unroll
      for (int kt=0; kt<8; kt++){
        s16x8 an[4], bn[4];
        if (kt < 7){
          #pragma unroll
          for (int rt=0;rt<4;rt++) an[rt] = *(const s16x8*)&Ys[rt*16+lr][(kt+1)*32 + lq*8];
        }
        if (kt < 6){
          #pragma unroll
          for (int ct=0;ct<4;ct++) bn[ct] = W2v[(size_t)((kt+2)*16 + wv*4 + ct)*64 + l];
        }
        #pragma unroll
        for (int rt=0; rt<4; rt++)
          #pragma unroll
          for (int ct=0; ct<4; ct++)
            acc2[rt][ct] = __builtin_amdgcn_mfma_f32_16x16x32_bf16(a0[rt], b0[ct], acc2[rt][ct], 0,0,0);
        #pragma unroll
        for (int i=0;i<4;i++){ a0[i]=an[i]; b0[i]=b1[i]; b1[i]=bn[i]; }
      }
    }

    if (dir==0){
      #pragma unroll
      for (int rt=0; rt<4; rt++)
        #pragma unroll
        for (int ct=0; ct<4; ct++) fsv[rt][ct] = acc2[rt][ct];
      __syncthreads();
    } else {
      __syncthreads();
      #pragma unroll
      for (int rt=0; rt<4; rt++)
        #pragma unroll
        for (int ct=0; ct<4; ct++)
          #pragma unroll
          for (int r=0; r<4; r++)
            Ys[rt*16 + lq*4 + r][cbase + ct*16 + lr] = f2bf(fsv[rt][ct][r] + acc2[rt][ct][r]);
      __syncthreads();
      short* dst = efb + (size_t)e0*MSGD;
      for (int i=t; i<64*32; i+=256){
        int row = i>>5, c8 = (i&31)*8;
        *(s16x8*)&dst[(size_t)row*MSGD + c8] = *(const s16x8*)&Ys[row][c8];
      }
    }
  }
}

// ---------------- GRU (256-thread, gate-aligned column tiles) ----------------
__global__ void __launch_bounds__(256,2) k_gru(const float* __restrict__ h,
    const short* __restrict__ hb, const short* __restrict__ aggb,
    const short* __restrict__ wih_p, const float* __restrict__ bih,
    const short* __restrict__ whh_p, const float* __restrict__ bhh,
    float* __restrict__ hnew, short* __restrict__ hnewb){
  __shared__ __align__(16) short aggs[64][264];
  __shared__ __align__(16) short hs[64][136];
  int t = threadIdx.x;
  int n0 = blockIdx.x*64;
  for (int i=t; i<64*32; i+=256){
    int r = i>>5, c8 = (i&31)*8;
    *(s16x8*)&aggs[r][c8] = *(const s16x8*)&aggb[(size_t)(n0+r)*MSGD + c8];
  }
  for (int i=t; i<64*16; i+=256){
    int r = i>>4, c8 = (i&15)*8;
    *(s16x8*)&hs[r][c8] = *(const s16x8*)&hb[(size_t)(n0+r)*HD + c8];
  }
  __syncthreads();

  int wv = t>>6, l = t&63, lr = l&15, lq = l>>4;
  const s16x8* Wih_v = (const s16x8*)wih_p;
  const s16x8* Whh_v = (const s16x8*)whh_p;

  f32x4 gi[4][6], gh[4][6];
  #pragma unroll
  for (int ct=0; ct<6; ct++){
    int bcol = (ct>>1)*128 + wv*32 + (ct&1)*16 + lr;
    float bi = bih[bcol], bh = bhh[bcol];
    #pragma unroll
    for (int rt=0; rt<4; rt++){
      gi[rt][ct] = (f32x4){bi,bi,bi,bi};
      gh[rt][ct] = (f32x4){bh,bh,bh,bh};
    }
  }
  for (int kt=0; kt<8; kt++){
    s16x8 af[4], bfr[6];
    #pragma unroll
    for (int rt=0; rt<4; rt++) af[rt] = *(const s16x8*)&aggs[rt*16+lr][kt*32 + lq*8];
    #pragma unroll
    for (int ct=0; ct<6; ct++){
      int nt = (ct>>1)*8 + wv*2 + (ct&1);
      bfr[ct] = Wih_v[(size_t)(kt*24 + nt)*64 + l];
    }
    #pragma unroll
    for (int rt=0; rt<4; rt++)
      #pragma unroll
      for (int ct=0; ct<6; ct++)
        gi[rt][ct] = __builtin_amdgcn_mfma_f32_16x16x32_bf16(af[rt], bfr[ct], gi[rt][ct], 0,0,0);
  }
  for (int kt=0; kt<4; kt++){
    s16x8 af[4], bfr[6];
    #pragma unroll
    for (int rt=0; rt<4; rt++) af[rt] = *(const s16x8*)&hs[rt*16+lr][kt*32 + lq*8];
    #pragma unroll
    for (int ct=0; ct<6; ct++){
      int nt = (ct>>1)*8 + wv*2 + (ct&1);
      bfr[ct] = Whh_v[(size_t)(kt*24 + nt)*64 + l];
    }
    #pragma unroll
    for (int rt=0; rt<4; rt++)
      #pragma unroll
      for (int ct=0; ct<6; ct++)
        gh[rt][ct] = __builtin_amdgcn_mfma_f32_16x16x32_bf16(af[rt], bfr[ct], gh[rt][ct], 0,0,0);
  }
  #pragma unroll
  for (int rt=0; rt<4; rt++)
    #pragma unroll
    for (int j=0; j<2; j++)
      #pragma unroll
      for (int r=0; r<4; r++){
        int row = n0 + rt*16 + lq*4 + r;
        int col = wv*32 + j*16 + lr;
        float rr = 1.f/(1.f + __expf(-(gi[rt][j][r]   + gh[rt][j][r])));
        float zz = 1.f/(1.f + __expf(-(gi[rt][2+j][r] + gh[rt][2+j][r])));
        float gn = gi[rt][4+j][r] + rr*gh[rt][4+j][r];
        float nn = 1.f - 2.f/(__expf(2.f*gn) + 1.f);   // tanh
        float hold = h[(size_t)row*HD + col];
        float hv = (1.f - zz)*nn + zz*hold;
        hnew[(size_t)row*HD + col] = hv;
        hnewb[(size_t)row*HD + col] = f2bf(hv);
      }
}

// ---------------- SK transform, bf16 MFMA (bf16 e_fin input) ----------------
__global__ void __launch_bounds__(256,2) k_tall(const short* __restrict__ efb,
    const short* __restrict__ W1p, const float* __restrict__ b1,
    const short* __restrict__ W2p, const float* __restrict__ b2,
    float* __restrict__ tall){
  __shared__ __align__(16) short Xs[64][264];
  __shared__ __align__(16) short Ys[64][40];
  int t = threadIdx.x;
  int g = blockIdx.x>>2, r0 = (blockIdx.x&3)*64;
  for (int i=t; i<64*32; i+=256){
    int r = i>>5, c8 = (i&31)*8;
    int row = r0 + r;
    s16x8 v = (row < EPG) ? *(const s16x8*)&efb[((size_t)g*EPG + row)*MSGD + c8]
                          : (s16x8){0,0,0,0,0,0,0,0};
    *(s16x8*)&Xs[r][c8] = v;
  }
  __syncthreads();
  int wv = t>>6, l = t&63, lr = l&15, lq = l>>4;
  const s16x8* W1v = (const s16x8*)W1p;
  const s16x8* W2v = (const s16x8*)W2p;
  f32x4 acc[2];
  #pragma unroll
  for (int ct=0; ct<2; ct++){
    float bb = b1[ct*16 + lr];
    acc[ct] = (f32x4){bb,bb,bb,bb};
  }
  for (int kt=0; kt<8; kt++){
    s16x8 a = *(const s16x8*)&Xs[wv*16+lr][kt*32 + lq*8];
    #pragma unroll
    for (int ct=0; ct<2; ct++){
      s16x8 bfr = W1v[(size_t)(kt*2 + ct)*64 + l];
      acc[ct] = __builtin_amdgcn_mfma_f32_16x16x32_bf16(a, bfr, acc[ct], 0,0,0);
    }
  }
  #pragma unroll
  for (int ct=0; ct<2; ct++)
    #pragma unroll
    for (int r=0; r<4; r++)
      Ys[wv*16 + lq*4 + r][ct*16 + lr] = f2bf(fmaxf(acc[ct][r], 0.f));
  __syncthreads();
  f32x4 acc2[2];
  #pragma unroll
  for (int ct=0; ct<2; ct++){
    float bb = b2[ct*16 + lr];
    acc2[ct] = (f32x4){bb,bb,bb,bb};
  }
  {
    s16x8 a = *(const s16x8*)&Ys[wv*16+lr][lq*8];
    #pragma unroll
    for (int ct=0; ct<2; ct++){
      s16x8 bfr = W2v[(size_t)ct*64 + l];
      acc2[ct] = __builtin_amdgcn_mfma_f32_16x16x32_bf16(a, bfr, acc2[ct], 0,0,0);
    }
  }
  #pragma unroll
  for (int ct=0; ct<2; ct++)
    #pragma unroll
    for (int r=0; r<4; r++){
      int row = r0 + wv*16 + lq*4 + r;
      tall[((size_t)g*256 + row)*SKD + ct*16 + lr] = (row < EPG) ? acc2[ct][r] : 0.f;
    }
}

// ---------------- Sinkhorn fused with la-init; 4-row-group matmul ----------------
__global__ void __attribute__((amdgpu_waves_per_eu(4,4))) __launch_bounds__(1024)
k_sinkhorn(const float* __restrict__ tall, short* __restrict__ plan){
  __shared__ float tqs[256*32];
  __shared__ float tcsT[32*257];
  __shared__ float cv[256];
  __shared__ float psm[16][256];
  int p = blockIdx.x, t = threadIdx.x;
  int w = t>>6, l = t&63;
  int rbase = w*16;
  const float* tq = tall + (size_t)(2*p)*8192;
  const float* tc = tall + (size_t)(2*p+1)*8192;
  for (int i=t; i<8192; i+=1024){
    tqs[i] = tq[i];
    tcsT[(i&31)*257 + (i>>5)] = tc[i];
  }
  __syncthreads();
  float4 E[16];
  #pragma unroll
  for (int kg=0; kg<4; kg++){
    float4 a0_ = {0.f,0.f,0.f,0.f}, a1_ = a0_, a2_ = a0_, a3_ = a0_;
    for (int kk=0; kk<32; kk+=4){
      float4 c0 = *(const float4*)&tcsT[(kk+0)*257 + 4*l];
      float4 c1 = *(const float4*)&tcsT[(kk+1)*257 + 4*l];
      float4 c2 = *(const float4*)&tcsT[(kk+2)*257 + 4*l];
      float4 c3 = *(const float4*)&tcsT[(kk+3)*257 + 4*l];
      float4 q0 = *(const float4*)&tqs[(rbase+kg*4+0)*32 + kk];
      float4 q1 = *(const float4*)&tqs[(rbase+kg*4+1)*32 + kk];
      float4 q2 = *(const float4*)&tqs[(rbase+kg*4+2)*32 + kk];
      float4 q3 = *(const float4*)&tqs[(rbase+kg*4+3)*32 + kk];
      a0_.x = fmaf(q0.x,c0.x, fmaf(q0.y,c1.x, fmaf(q0.z,c2.x, fmaf(q0.w,c3.x, a0_.x))));
      a0_.y = fmaf(q0.x,c0.y, fmaf(q0.y,c1.y, fmaf(q0.z,c2.y, fmaf(q0.w,c3.y, a0_.y))));
      a0_.z = fmaf(q0.x,c0.z, fmaf(q0.y,c1.z, fmaf(q0.z,c2.z, fmaf(q0.w,c3.z, a0_.z))));
      a0_.w = fmaf(q0.x,c0.w, fmaf(q0.y,c1.w, fmaf(q0.z,c2.w, fmaf(q0.w,c3.w, a0_.w))));
      a1_.x = fmaf(q1.x,c0.x, fmaf(q1.y,c1.x, fmaf(q1.z,c2.x, fmaf(q1.w,c3.x, a1_.x))));
      a1_.y = fmaf(q1.x,c0.y, fmaf(q1.y,c1.y, fmaf(q1.z,c2.y, fmaf(q1.w,c3.y, a1_.y))));
      a1_.z = fmaf(q1.x,c0.z, fmaf(q1.y,c1.z, fmaf(q1.z,c2.z, fmaf(q1.w,c3.z, a1_.z))));
      a1_.w = fmaf(q1.x,c0.w, fmaf(q1.y,c1.w, fmaf(q1.z,c2.w, fmaf(q1.w,c3.w, a1_.w))));
      a2_.x = fmaf(q2.x,c0.x, fmaf(q2.y,c1.x, fmaf(q2.z,c2.x, fmaf(q2.w,c3.x, a2_.x))));
      a2_.y = fmaf(q2.x,c0.y, fmaf(q2.y,c1.y, fmaf(q2.z,c2.y, fmaf(q2.w,c3.y, a2_.y))));
      a2_.z = fmaf(q2.x,c0.z, fmaf(q2.y,c1.z, fmaf(q2.z,c2.z, fmaf(q2.w,c3.z, a2_.z))));
      a2_.w = fmaf(q2.x,c0.w, fmaf(q2.y,c1.w, fmaf(q2.z,c2.w, fmaf(q2.w,c3.w, a2_.w))));
      a3_.x = fmaf(q3.x,c0.x, fmaf(q3.y,c1.x, fmaf(q3.z,c2.x, fmaf(q3.w,c3.x, a3_.x))));
      a3_.y = fmaf(q3.x,c0.y, fmaf(q3.y,c1.y, fmaf(q3.z,c2.y, fmaf(q3.w,c3.y, a3_.y))));
      a3_.z = fmaf(q3.x,c0.z, fmaf(q3.y,c1.z, fmaf(q3.z,c2.z, fmaf(q3.w,c3.z, a3_.z))));
      a3_.w = fmaf(q3.x,c0.w, fmaf(q3.y,c1.w, fmaf(q3.z,c2.w, fmaf(q3.w,c3.w, a3_.w))));
    }
    #pragma unroll
    for (int j=0; j<4; j++){
      float4 a = (j==0)?a0_:(j==1)?a1_:(j==2)?a2_:a3_;
      a.x *= 10.f; a.y *= 10.f; a.z *= 10.f; a.w *= 10.f;
      float m = fmaxf(fmaxf(a.x,a.y), fmaxf(a.z,a.w));
      #pragma unroll
      for (int off=32; off; off>>=1) m = fmaxf(m, __shfl_xor(m, off));
      float s = __expf(a.x-m)+__expf(a.y-m)+__expf(a.z-m)+__expf(a.w-m);
      #pragma unroll
      for (int off=32; off; off>>=1) s += __shfl_xor(s, off);
      float r = m + __logf(s);
      E[kg*4+j].x = __expf(a.x - r); E[kg*4+j].y = __expf(a.y - r);
      E[kg*4+j].z = __expf(a.z - r); E[kg*4+j].w = __expf(a.w - r);
    }
  }

  for (int it=0; it<20; it++){
    float4 sm = {0.f,0.f,0.f,0.f};
    #pragma unroll
    for (int k=0;k<16;k++){
      sm.x += E[k].x; sm.y += E[k].y; sm.z += E[k].z; sm.w += E[k].w;
    }
    *(float4*)&psm[w][4*l] = sm;
    __syncthreads();
    if (t < 256){
      float s = psm[0][t];
      #pragma unroll
      for (int ww=1; ww<16; ww++) s += psm[ww][t];
      cv[t] = frcp(s);
    }
    __syncthreads();
    float4 ic = *(const float4*)&cv[4*l];
    #pragma unroll
    for (int k=0;k<16;k++){
      E[k].x *= ic.x; E[k].y *= ic.y; E[k].z *= ic.z; E[k].w *= ic.w;
    }
    if (it < 19){
      #pragma unroll
      for (int k=0;k<16;k++){
        float s = E[k].x + E[k].y + E[k].z + E[k].w;
        #pragma unroll
        for (int off=32; off; off>>=1) s += __shfl_xor(s, off);
        float inv = frcp(s);
        E[k].x *= inv; E[k].y *= inv; E[k].z *= inv; E[k].w *= inv;
      }
    }
  }
  short* P = plan + (size_t)p*65536;
  #pragma unroll
  for (int k=0;k<16;k++){
    s16x4 o;
    o[0]=f2bf(E[k].x); o[1]=f2bf(E[k].y); o[2]=f2bf(E[k].z); o[3]=f2bf(E[k].w);
    *(s16x4*)&P[(size_t)(rbase+k)*256 + 4*l] = o;
  }
}

// ---------------- loss: bf16 plan @ bf16 c, fused relu-reduce ----------------
__global__ void __launch_bounds__(256,2) k_loss(const short* __restrict__ plan,
    const short* __restrict__ efb, float* __restrict__ out){
  __shared__ __align__(16) short Ps[128][40];
  __shared__ __align__(16) short Cs[256][40];
  __shared__ float red[4];
  int t = threadIdx.x;
  int b = blockIdx.x, p = b>>1, rh = b&1;
  int i0 = rh*128;
  int wv = t>>6, l = t&63, lr = l&15, lq = l>>4;
  const short* Pb = plan + (size_t)p*65536;
  const unsigned short* C = (const unsigned short*)(efb + (size_t)(2*p+1)*EPG*MSGD);
  const unsigned short* Q = (const unsigned short*)(efb + (size_t)(2*p)*EPG*MSGD);

  f32x4 acc[2][16];
  #pragma unroll
  for (int rt=0;rt<2;rt++)
    #pragma unroll
    for (int ct=0;ct<16;ct++) acc[rt][ct] = (f32x4){0.f,0.f,0.f,0.f};

  for (int kt=0; kt<8; kt++){
    __syncthreads();
    for (int i=t; i<128*4; i+=256){
      int r = i>>2, c8 = (i&3)*8;
      *(s16x8*)&Ps[r][c8] = *(const s16x8*)&Pb[(size_t)(i0+r)*256 + kt*32 + c8];
    }
    for (int i=t; i<32*64; i+=256){
      int k = i>>6, c4 = (i&63)*4;
      int j = kt*32 + k;
      ushort4 v = (j < EPG) ? *(const ushort4*)&C[(size_t)j*256 + c4] : (ushort4){0,0,0,0};
      Cs[c4+0][k]=(short)v.x; Cs[c4+1][k]=(short)v.y; Cs[c4+2][k]=(short)v.z; Cs[c4+3][k]=(short)v.w;
    }
    __syncthreads();
    s16x8 a0 = *(const s16x8*)&Ps[wv*32      + lr][lq*8];
    s16x8 a1 = *(const s16x8*)&Ps[wv*32 + 16 + lr][lq*8];
    #pragma unroll
    for (int ct=0; ct<16; ct++){
      s16x8 bfr = *(const s16x8*)&Cs[ct*16+lr][lq*8];
      acc[0][ct] = __builtin_amdgcn_mfma_f32_16x16x32_bf16(a0, bfr, acc[0][ct], 0,0,0);
      acc[1][ct] = __builtin_amdgcn_mfma_f32_16x16x32_bf16(a1, bfr, acc[1][ct], 0,0,0);
    }
  }
  float s = 0.f;
  #pragma unroll
  for (int rt=0; rt<2; rt++)
    #pragma unroll
    for (int ct=0; ct<16; ct++)
      #pragma unroll
      for (int r=0; r<4; r++){
        int row = i0 + wv*32 + rt*16 + lq*4 + r;
        int col = ct*16 + lr;
        float q = (row < EPG) ? bf2f(Q[(size_t)row*256 + col]) : 0.f;
        s += fmaxf(q - acc[rt][ct][r], 0.f);
      }
  #pragma unroll
  for (int off=32; off; off>>=1) s += __shfl_xor(s, off);
  if (l==0) red[wv] = s;
  __syncthreads();
  if (t==0) atomicAdd(&out[p], -(red[0]+red[1]+red[2]+red[3]));
}

// ---------------- launch ----------------
extern "C" void kernel_launch(void* const* d_in, const int* in_sizes, int n_in,
                              void* d_out, int out_size, void* d_ws, size_t ws_size,
                              hipStream_t stream){
  const float* nf   = (const float*)d_in[0];
  const float* ef   = (const float*)d_in[1];
  const int*   fidx = (const int*)d_in[2];
  const int*   tidx = (const int*)d_in[3];
  const float* enw  = (const float*)d_in[4];
  const float* enb  = (const float*)d_in[5];
  const float* eew  = (const float*)d_in[6];
  const float* eeb_w= (const float*)d_in[7];
  const float* mw1  = (const float*)d_in[8];
  const float* mb1  = (const float*)d_in[9];
  const float* mw2  = (const float*)d_in[10];
  const float* mb2  = (const float*)d_in[11];
  const float* rw1  = (const float*)d_in[12];
  const float* rb1  = (const float*)d_in[13];
  const float* rw2  = (const float*)d_in[14];
  const float* rb2  = (const float*)d_in[15];
  const float* wih  = (const float*)d_in[16];
  const float* bih  = (const float*)d_in[17];
  const float* whh  = (const float*)d_in[18];
  const float* bhh  = (const float*)d_in[19];
  const float* skw1 = (const float*)d_in[20];
  const float* skb1 = (const float*)d_in[21];
  const float* skw2 = (const float*)d_in[22];
  const float* skb2 = (const float*)d_in[23];
  float* out = (float*)d_out;

  float* ws = (float*)d_ws;
  float* h_a   = ws;                               // NN*HD f
  float* h_b   = h_a + (size_t)NN*HD;              // NN*HD f
  short* hb_a  = (short*)(h_b + (size_t)NN*HD);    // NN*HD sh
  short* hb_b  = hb_a + (size_t)NN*HD;             // NN*HD sh
  short* ee_b  = hb_b + (size_t)NN*HD;             // NE*EED sh
  short* mf    = ee_b + (size_t)NE*EED;            // NE*MSGD sh
  short* mr    = mf + (size_t)NE*MSGD;             // NE*MSGD sh
  short* e_finb = mf;                              // alias (mf/mr dead after loop)
  float* t_all = (float*)(mr + (size_t)NE*MSGD);   // NG*256*SKD f
  float* la    = t_all + (size_t)NG*256*SKD;       // plan/agg/skw region

  short* w1f_p = (short*)t_all;
  short* w1r_p = w1f_p + 320*256;
  short* w2f_p = w1r_p + 320*256;
  short* w2r_p = w2f_p + 256*256;
  short* wih_p = w2r_p + 256*256;
  short* whh_p = wih_p + 256*384;
  int*   csr   = (int*)(t_all + 221184);
  int* cur_in    = csr;
  int* cur_out   = cur_in  + NN;
  int* start_in  = cur_out + NN;
  int* start_out = start_in + NN;
  int* list_in   = start_out + NN;
  int* list_out  = list_in + NE;

  short* aggb   = (short*)la;                      // NN*MSGD sh (loop phase)
  short* plan_s = (short*)la;                      // NP*65536 sh (after loop)
  short* skw1_p = (short*)(la + 9000000);
  short* skw2_p = skw1_p + 256*32;

  k_pack_all<<<221, 256, 0, stream>>>(mw1, rw1, mw2, rw2, wih, whh, skw1, skw2,
      w1f_p, w1r_p, w2f_p, w2r_p, wih_p, whh_p, skw1_p, skw2_p);

  k_enc_node<<<NN/2, 256, 0, stream>>>(nf, enw, enb, h_a, hb_a);
  k_enc_edge<<<NE/4, 256, 0, stream>>>(ef, eew, eeb_w, ee_b);

  hipMemsetAsync(csr, 0, (size_t)2*NN*sizeof(int), stream);
  k_csr_count<<<NE/256, 256, 0, stream>>>(fidx, tidx, cur_in, cur_out);
  k_csr_scan<<<NG, 64, 0, stream>>>(cur_in, start_in, cur_out, start_out);
  k_csr_fill<<<NE/256, 256, 0, stream>>>(fidx, tidx, cur_in, cur_out, list_in, list_out);

  float* hc = h_a; float* hn = h_b;
  short* hbc = hb_a; short* hbn = hb_b;
  for (int step=0; step<5; step++){
    k_msg_both<<<NE/64, 256, 0, stream>>>(hbc, ee_b, fidx, tidx,
        w1f_p, mb1, w2f_p, mb2, w1r_p, rb1, w2r_p, rb2, mf, mr);
    k_gather<<<NN/4, 256, 0, stream>>>((const unsigned short*)mf, (const unsigned short*)mr,
        start_in, cur_in, list_in, start_out, cur_out, list_out, aggb);
    k_gru<<<NN/64, 256, 0, stream>>>(hc, hbc, aggb, wih_p, bih, whh_p, bhh, hn, hbn);
    float* tmp = hc; hc = hn; hn = tmp;
    short* tmb = hbc; hbc = hbn; hbn = tmb;
  }
  k_msg_fin<<<NE/64, 256, 0, stream>>>(hbc, ee_b, fidx, tidx,
      w1f_p, mb1, w2f_p, mb2, w1r_p, rb1, w2r_p, rb2, e_finb);

  k_tall<<<NG*4, 256, 0, stream>>>(e_finb, skw1_p, skb1, skw2_p, skb2, t_all);
  k_sinkhorn<<<NP, 1024, 0, stream>>>(t_all, plan_s);

  hipMemsetAsync(out, 0, (size_t)NP*sizeof(float), stream);
  k_loss<<<NP*2, 256, 0, stream>>>(plan_s, e_finb, out);
}